// Round 3
// baseline (4882.661 us; speedup 1.0000x reference)
//
#include <hip/hip_runtime.h>
#include <stdint.h>

#define B_ 4096
#define D_ 512
#define H_ 2048

typedef unsigned short ushort_t;
typedef __attribute__((ext_vector_type(8))) short bf16x8;
typedef __attribute__((ext_vector_type(4))) float f32x4;

__device__ __forceinline__ ushort_t f2bf(float f) {
  union { float f; uint32_t u; } v; v.f = f;
  uint32_t u = v.u;
  return (ushort_t)((u + 0x7fffu + ((u >> 16) & 1u)) >> 16);  // RNE, finite inputs
}

__device__ __forceinline__ ushort4 pack4(float a, float b, float c, float d) {
  ushort4 r; r.x = f2bf(a); r.y = f2bf(b); r.z = f2bf(c); r.w = f2bf(d); return r;
}

// tanh(x) = 1 - 2/(e^{2x}+1); exp->inf => 1, exp->0 => -1 (no NaN at extremes)
__device__ __forceinline__ float fast_tanh(float x) {
  float t = __expf(2.0f * x);
  return 1.0f - 2.0f * __builtin_amdgcn_rcpf(t + 1.0f);
}

// async global->LDS, 16B/lane; LDS dest = wave-uniform base + lane*16
__device__ __forceinline__ void gl2lds16(const ushort_t* g, ushort_t* l) {
  __builtin_amdgcn_global_load_lds(
      (const __attribute__((address_space(1))) unsigned int*)(const void*)g,
      (__attribute__((address_space(3))) unsigned int*)(void*)l,
      16, 0, 0);
}

// ---------------------------------------------------------------------------
// GEMM1: T[B][H] = bf16(tanh(Abf[B][D] * W1t[H][D]^T + b1)).
// Tile 128x128, BK=32, K=512 (16 iters), 4 waves of 64x64, grid (32,16).
// Double-buffered LDS (2x16KB), prefetch issued before compute phase.
// ---------------------------------------------------------------------------
__global__ __launch_bounds__(256)
void gemm1_tanh(const ushort_t* __restrict__ A, const ushort_t* __restrict__ Bt,
                const float* __restrict__ b1, ushort_t* __restrict__ T)
{
  __shared__ __align__(16) ushort_t As[2][128 * 32];
  __shared__ __align__(16) ushort_t Bs[2][128 * 32];
  const int t  = threadIdx.x;
  const int bm = blockIdx.x, bn = blockIdx.y;
  const int l  = t & 63, w = t >> 6;
  const int wm = (w & 1) * 64, wn = (w >> 1) * 64;
  const int lm = l & 15, kg = l >> 4;

  f32x4 acc[4][4];
#pragma unroll
  for (int i = 0; i < 4; ++i)
#pragma unroll
    for (int j = 0; j < 4; ++j) acc[i][j] = (f32x4)(0.f);

  // staging: wave w stages 1KB chunks {2w,2w+1} of As and Bs
  // chunk c covers rows 16c..16c+15; lane i -> row 16c + i/4, col (i%4)*8
  const int c0 = 2 * w, c1 = c0 + 1;
  const int sr0 = c0 * 16 + (l >> 2), sr1 = c1 * 16 + (l >> 2);
  const int sc = (l & 3) * 8;
  const ushort_t* Ab = A  + (size_t)(bm * 128) * D_;
  const ushort_t* Bb = Bt + (size_t)(bn * 128) * D_;

  gl2lds16(Ab + (size_t)sr0 * D_ + sc, As[0] + c0 * 512);
  gl2lds16(Ab + (size_t)sr1 * D_ + sc, As[0] + c1 * 512);
  gl2lds16(Bb + (size_t)sr0 * D_ + sc, Bs[0] + c0 * 512);
  gl2lds16(Bb + (size_t)sr1 * D_ + sc, Bs[0] + c1 * 512);

  for (int k = 0; k < 16; ++k) {
    __syncthreads();   // drains vmcnt(0): buf[k&1] staged; other buf read-free
    const int kn = k + 1;
    if (kn < 16) {     // early prefetch into the other buffer (overlaps compute)
      const int kk = kn * 32;
      gl2lds16(Ab + (size_t)sr0 * D_ + kk + sc, As[kn & 1] + c0 * 512);
      gl2lds16(Ab + (size_t)sr1 * D_ + kk + sc, As[kn & 1] + c1 * 512);
      gl2lds16(Bb + (size_t)sr0 * D_ + kk + sc, Bs[kn & 1] + c0 * 512);
      gl2lds16(Bb + (size_t)sr1 * D_ + kk + sc, Bs[kn & 1] + c1 * 512);
    }
    const ushort_t* as = As[k & 1];
    const ushort_t* bs = Bs[k & 1];
    bf16x8 af[4], bv[4];
#pragma unroll
    for (int i = 0; i < 4; ++i)
      af[i] = *(const bf16x8*)(as + (wm + i * 16 + lm) * 32 + kg * 8);
#pragma unroll
    for (int j = 0; j < 4; ++j)
      bv[j] = *(const bf16x8*)(bs + (wn + j * 16 + lm) * 32 + kg * 8);
#pragma unroll
    for (int i = 0; i < 4; ++i)
#pragma unroll
      for (int j = 0; j < 4; ++j)
        acc[i][j] = __builtin_amdgcn_mfma_f32_16x16x32_bf16(af[i], bv[j], acc[i][j], 0, 0, 0);
  }

  const int r0 = (l >> 4) * 4;   // C/D: col = lane&15, row = (lane>>4)*4 + reg
#pragma unroll
  for (int i = 0; i < 4; ++i) {
#pragma unroll
    for (int j = 0; j < 4; ++j) {
      const int gcol = bn * 128 + wn + j * 16 + lm;
      const float bias = b1[gcol];
#pragma unroll
      for (int r = 0; r < 4; ++r) {
        const int grow = bm * 128 + wm + i * 16 + r0 + r;
        T[(size_t)grow * H_ + gcol] = f2bf(fast_tanh(acc[i][j][r] + bias));
      }
    }
  }
}

// ---------------------------------------------------------------------------
// GEMM2 + fused integrator epilogue.
// f[B][D] = T[B][H] * W2t[D][H]^T + b2, then per-element MODE op:
//  0 E1:   hnew=f; SP=f;            abf=bf16(y + s0*f)
//  1 E23:  SP+=2f;                  abf=bf16(y + s0*f)
//  2 E4:   yn=y+s0*(SP+f); yout=yn; abf=bf16(yn)
//  3 PRED: hnew=f; SP=y+s0*(19f-5h1+h2); abf=bf16(y+s0*(55f-59h1+37h2-9h3))
//  4 CORR:                          abf=bf16(SP + s0*f)
//  5 FIN:  yn=SP+s0*f; yout=yn;     abf=bf16(yn) if abf
// Tile 128x64, BK=32, K=2048 (64 iters), 4 waves of 64x32, grid (32,8).
// Double-buffered LDS (2x12KB), early prefetch.
// ---------------------------------------------------------------------------
template<int MODE>
__global__ __launch_bounds__(256)
void gemm2_fused(const ushort_t* __restrict__ A, const ushort_t* __restrict__ Bt,
                 const float* __restrict__ b2,
                 const float* y, const float* __restrict__ h1,
                 const float* __restrict__ h2, const float* __restrict__ h3,
                 float* SP, float* __restrict__ hnew,
                 float* yout, ushort_t* __restrict__ abf, float s0)
{
  __shared__ __align__(16) ushort_t As[2][128 * 32];
  __shared__ __align__(16) ushort_t Bs[2][64 * 32];
  const int t  = threadIdx.x;
  const int bm = blockIdx.x, bn = blockIdx.y;
  const int l  = t & 63, w = t >> 6;
  const int wm = (w & 1) * 64, wn = (w >> 1) * 32;
  const int lm = l & 15, kg = l >> 4;

  f32x4 acc[4][2];
#pragma unroll
  for (int i = 0; i < 4; ++i)
#pragma unroll
    for (int j = 0; j < 2; ++j) acc[i][j] = (f32x4)(0.f);

  // staging: wave w stages A chunks {2w,2w+1} (8 total) and B chunk w (4 total)
  const int c0 = 2 * w, c1 = c0 + 1;
  const int sra0 = c0 * 16 + (l >> 2), sra1 = c1 * 16 + (l >> 2);
  const int srb  = w  * 16 + (l >> 2);
  const int sc = (l & 3) * 8;
  const ushort_t* Ab = A  + (size_t)(bm * 128) * H_;
  const ushort_t* Bb = Bt + (size_t)(bn * 64) * H_;

  gl2lds16(Ab + (size_t)sra0 * H_ + sc, As[0] + c0 * 512);
  gl2lds16(Ab + (size_t)sra1 * H_ + sc, As[0] + c1 * 512);
  gl2lds16(Bb + (size_t)srb  * H_ + sc, Bs[0] + w * 512);

  for (int k = 0; k < 64; ++k) {
    __syncthreads();
    const int kn = k + 1;
    if (kn < 64) {
      const int kk = kn * 32;
      gl2lds16(Ab + (size_t)sra0 * H_ + kk + sc, As[kn & 1] + c0 * 512);
      gl2lds16(Ab + (size_t)sra1 * H_ + kk + sc, As[kn & 1] + c1 * 512);
      gl2lds16(Bb + (size_t)srb  * H_ + kk + sc, Bs[kn & 1] + w * 512);
    }
    const ushort_t* as = As[k & 1];
    const ushort_t* bs = Bs[k & 1];
    bf16x8 af[4], bv[2];
#pragma unroll
    for (int i = 0; i < 4; ++i)
      af[i] = *(const bf16x8*)(as + (wm + i * 16 + lm) * 32 + kg * 8);
#pragma unroll
    for (int j = 0; j < 2; ++j)
      bv[j] = *(const bf16x8*)(bs + (wn + j * 16 + lm) * 32 + kg * 8);
#pragma unroll
    for (int i = 0; i < 4; ++i)
#pragma unroll
      for (int j = 0; j < 2; ++j)
        acc[i][j] = __builtin_amdgcn_mfma_f32_16x16x32_bf16(af[i], bv[j], acc[i][j], 0, 0, 0);
  }

  const int r0 = (l >> 4) * 4;
#pragma unroll
  for (int i = 0; i < 4; ++i) {
#pragma unroll
    for (int j = 0; j < 2; ++j) {
      const int gcol = bn * 64 + wn + j * 16 + lm;
      const float bias = b2[gcol];
#pragma unroll
      for (int r = 0; r < 4; ++r) {
        const int grow = bm * 128 + wm + i * 16 + r0 + r;
        const size_t idx = (size_t)grow * D_ + gcol;
        const float f = acc[i][j][r] + bias;
        if constexpr (MODE == 0) {
          hnew[idx] = f; SP[idx] = f;
          abf[idx] = f2bf(y[idx] + s0 * f);
        } else if constexpr (MODE == 1) {
          SP[idx] += 2.f * f;
          abf[idx] = f2bf(y[idx] + s0 * f);
        } else if constexpr (MODE == 2) {
          float yn = y[idx] + s0 * (SP[idx] + f);
          yout[idx] = yn; abf[idx] = f2bf(yn);
        } else if constexpr (MODE == 3) {
          hnew[idx] = f;
          float yv = y[idx], a1 = h1[idx], a2 = h2[idx], a3 = h3[idx];
          SP[idx] = yv + s0 * (19.f * f - 5.f * a1 + a2);
          abf[idx] = f2bf(yv + s0 * (55.f * f - 59.f * a1 + 37.f * a2 - 9.f * a3));
        } else if constexpr (MODE == 4) {
          abf[idx] = f2bf(SP[idx] + s0 * f);
        } else {
          float yn = SP[idx] + s0 * f;
          yout[idx] = yn;
          if (abf) abf[idx] = f2bf(yn);
        }
      }
    }
  }
}

// ---------------------------------------------------------------------------
template<int R, int C>
__global__ void k_transpose(const float* __restrict__ W, ushort_t* __restrict__ Wt) {
  const int tid = blockIdx.x * 256 + threadIdx.x;   // tid = c*R + r
  if (tid >= R * C) return;
  const int r = tid % R;
  const int c = tid / R;
  Wt[tid] = f2bf(W[(size_t)r * C + c]);
}

__global__ void k_cvt(const float4* __restrict__ src, ushort4* __restrict__ abf, int n4) {
  int i = blockIdx.x * 256 + threadIdx.x;
  if (i >= n4) return;
  float4 v = src[i];
  abf[i] = pack4(v.x, v.y, v.z, v.w);
}

// ---------------------------------------------------------------------------
extern "C" void kernel_launch(void* const* d_in, const int* in_sizes, int n_in,
                              void* d_out, int out_size, void* d_ws, size_t ws_size,
                              hipStream_t stream) {
  const float* x  = (const float*)d_in[0];
  const float* W1 = (const float*)d_in[1];
  const float* b1 = (const float*)d_in[2];
  const float* W2 = (const float*)d_in[3];
  const float* b2 = (const float*)d_in[4];
  float* out = (float*)d_out;

  uint8_t* ws = (uint8_t*)d_ws;
  const size_t MB = 1024 * 1024;
  ushort_t* W1t = (ushort_t*)(ws);            // [H][D] bf16, 2 MB
  ushort_t* W2t = (ushort_t*)(ws + 2 * MB);   // [D][H] bf16, 2 MB
  ushort_t* Abf = (ushort_t*)(ws + 4 * MB);   // GEMM1 input bf16 [B][D], 4 MB
  ushort_t* T   = (ushort_t*)(ws + 8 * MB);   // activations bf16 [B][H], 16 MB
  float* ybuf   = (float*)(ws + 24 * MB);     // state y (8 MB)
  float* Sbuf   = (float*)(ws + 32 * MB);     // ksum (RK4) / S (ABM) (8 MB)
  float* hb[4]  = { (float*)(ws + 40 * MB), (float*)(ws + 48 * MB),
                    (float*)(ws + 56 * MB), (float*)(ws + 64 * MB) };  // f-history

  const int n4 = B_ * D_ / 4;
  const float dt = 1.0f / 20.0f;
  const float c = dt / 24.0f, c9 = 9.0f * c, dt6 = dt / 6.0f;
  float* const NO_F = nullptr;
  ushort_t* const NO_U = nullptr;

  k_transpose<D_, H_><<<(D_ * H_) / 256, 256, 0, stream>>>(W1, W1t);
  k_transpose<H_, D_><<<(H_ * D_) / 256, 256, 0, stream>>>(W2, W2t);

  auto G1 = [&]() {
    gemm1_tanh<<<dim3(B_ / 128, H_ / 128), 256, 0, stream>>>(Abf, W1t, b1, T);
  };
  const dim3 G2G(B_ / 128, D_ / 64), G2B(256);

  // ---- Abf = bf16(x) ----
  k_cvt<<<n4 / 256, 256, 0, stream>>>((const float4*)x, (ushort4*)Abf, n4);

  // ---- RK4 bootstrap: 3 steps ----
  for (int s = 0; s < 3; ++s) {
    const float* yin = (s == 0) ? x : (const float*)ybuf;
    G1();  // eval f(y_s) = k1
    gemm2_fused<0><<<G2G, G2B, 0, stream>>>(T, W2t, b2, yin, NO_F, NO_F, NO_F,
                                            Sbuf, hb[s], NO_F, Abf, 0.5f * dt);
    G1();  // k2
    gemm2_fused<1><<<G2G, G2B, 0, stream>>>(T, W2t, b2, yin, NO_F, NO_F, NO_F,
                                            Sbuf, NO_F, NO_F, Abf, 0.5f * dt);
    G1();  // k3
    gemm2_fused<1><<<G2G, G2B, 0, stream>>>(T, W2t, b2, yin, NO_F, NO_F, NO_F,
                                            Sbuf, NO_F, NO_F, Abf, dt);
    G1();  // k4 -> y_{s+1}
    gemm2_fused<2><<<G2G, G2B, 0, stream>>>(T, W2t, b2, yin, NO_F, NO_F, NO_F,
                                            Sbuf, NO_F, ybuf, Abf, dt6);
  }

  // ---- f(y_3) -> hb[3] + first predictor ----
  G1();
  gemm2_fused<3><<<G2G, G2B, 0, stream>>>(T, W2t, b2, ybuf, hb[2], hb[1], hb[0],
                                          Sbuf, hb[3], NO_F, Abf, c);

  // ---- ABM-4: 17 steps ----
  for (int st = 0; st < 17; ++st) {
    G1();  // f(pred0)
    gemm2_fused<4><<<G2G, G2B, 0, stream>>>(T, W2t, b2, NO_F, NO_F, NO_F, NO_F,
                                            Sbuf, NO_F, NO_F, Abf, c9);
    G1();  // f(pred1)
    gemm2_fused<4><<<G2G, G2B, 0, stream>>>(T, W2t, b2, NO_F, NO_F, NO_F, NO_F,
                                            Sbuf, NO_F, NO_F, Abf, c9);
    G1();  // f(pred2) -> pred3
    if (st == 16) {
      gemm2_fused<5><<<G2G, G2B, 0, stream>>>(T, W2t, b2, NO_F, NO_F, NO_F, NO_F,
                                              Sbuf, NO_F, out, NO_U, c9);
      break;
    }
    gemm2_fused<5><<<G2G, G2B, 0, stream>>>(T, W2t, b2, NO_F, NO_F, NO_F, NO_F,
                                            Sbuf, NO_F, ybuf, Abf, c9);
    const int m = st & 3;  // slot for the new h0
    G1();  // f(y_{n+1}) + predictor for next step
    gemm2_fused<3><<<G2G, G2B, 0, stream>>>(T, W2t, b2, ybuf,
                                            hb[(m + 3) & 3], hb[(m + 2) & 3], hb[(m + 1) & 3],
                                            Sbuf, hb[m], NO_F, Abf, c);
  }

  (void)in_sizes; (void)n_in; (void)out_size; (void)ws_size;
}